// Round 3
// baseline (2172.124 us; speedup 1.0000x reference)
//
#include <hip/hip_runtime.h>
#include <hip/hip_bf16.h>

#define N_NODES 400000
#define N_EDGES 800000
#define DIM 128
#define NLAYER 5
#define BN_EPS 1e-5f

typedef _Float16 half8 __attribute__((ext_vector_type(8)));
typedef float f32x4 __attribute__((ext_vector_type(4)));

// ---------------- embedding: h0 = emb_atom[x0] + emb_chir[x1] ----------------
__global__ __launch_bounds__(256) void k_embed(const int* __restrict__ x,
                                               const float* __restrict__ ea,
                                               const float* __restrict__ ec,
                                               float* __restrict__ out) {
  int idx = blockIdx.x * 256 + threadIdx.x;      // float4 index
  int i = idx >> 5, c4 = (idx & 31) * 4;
  int av = x[2 * i], cv = x[2 * i + 1];
  float4 va = *(const float4*)(ea + (size_t)av * DIM + c4);
  float4 vc = *(const float4*)(ec + (size_t)cv * DIM + c4);
  float4 r;
  r.x = va.x + vc.x; r.y = va.y + vc.y; r.z = va.z + vc.z; r.w = va.w + vc.w;
  *(float4*)(out + (size_t)i * DIM + c4) = r;
}

// ---------------- CSR build ----------------
__global__ __launch_bounds__(256) void k_hist(const int* __restrict__ dst, int* __restrict__ cnt) {
  int e = blockIdx.x * 256 + threadIdx.x;
  if (e < N_EDGES) atomicAdd(&cnt[dst[e]], 1);
}

__global__ __launch_bounds__(256) void k_scan1(const int* __restrict__ cnt, int* __restrict__ rp,
                                               int* __restrict__ part) {
  __shared__ int sm[256];
  int t = threadIdx.x;
  int base = blockIdx.x * 1024 + t * 4;
  int v0 = 0, v1 = 0, v2 = 0, v3 = 0;
  if (base + 4 <= N_NODES) {
    int4 v = *(const int4*)(cnt + base);
    v0 = v.x; v1 = v.y; v2 = v.z; v3 = v.w;
  } else {
    if (base     < N_NODES) v0 = cnt[base];
    if (base + 1 < N_NODES) v1 = cnt[base + 1];
    if (base + 2 < N_NODES) v2 = cnt[base + 2];
    if (base + 3 < N_NODES) v3 = cnt[base + 3];
  }
  int s = v0 + v1 + v2 + v3;
  sm[t] = s;
  __syncthreads();
  for (int off = 1; off < 256; off <<= 1) {
    int add = (t >= off) ? sm[t - off] : 0;
    __syncthreads();
    sm[t] += add;
    __syncthreads();
  }
  int incl = sm[t];
  int ex = incl - s;
  if (t == 255) part[blockIdx.x] = incl;
  if (base     < N_NODES) rp[base]     = ex;
  if (base + 1 < N_NODES) rp[base + 1] = ex + v0;
  if (base + 2 < N_NODES) rp[base + 2] = ex + v0 + v1;
  if (base + 3 < N_NODES) rp[base + 3] = ex + v0 + v1 + v2;
}

__global__ __launch_bounds__(512) void k_scan2(int* __restrict__ part, int nb) {
  __shared__ int sm[512];
  int t = threadIdx.x;
  int v = (t < nb) ? part[t] : 0;
  sm[t] = v;
  __syncthreads();
  for (int off = 1; off < 512; off <<= 1) {
    int add = (t >= off) ? sm[t - off] : 0;
    __syncthreads();
    sm[t] += add;
    __syncthreads();
  }
  if (t < nb) part[t] = sm[t] - v;   // exclusive
}

__global__ __launch_bounds__(256) void k_scan3(int* __restrict__ rp, const int* __restrict__ part) {
  int i = blockIdx.x * 256 + threadIdx.x;
  if (i < N_NODES) rp[i] += part[i >> 10];
  if (i == 0) rp[N_NODES] = N_EDGES;
}

__global__ __launch_bounds__(256) void k_scatter(const int* __restrict__ src, const int* __restrict__ dst,
                                                 const int* __restrict__ rp, int* __restrict__ fill,
                                                 int* __restrict__ es) {
  int e = blockIdx.x * 256 + threadIdx.x;
  if (e < N_EDGES) {
    int d = dst[e];
    int slot = rp[d] + atomicAdd(&fill[d], 1);
    es[slot] = src[e];
  }
}

// ---------------- W pre-transpose to fp16: wt[l][mat][c][k] = W[l][k][c] ----------------
__global__ __launch_bounds__(128) void k_wprep(const float* __restrict__ W1, const float* __restrict__ W2,
                                               _Float16* __restrict__ wt) {
  int b = blockIdx.x;                 // 5*2*128
  int l = b >> 8, mat = (b >> 7) & 1, c = b & 127;
  int k = threadIdx.x;                // 128
  const float* W = mat ? W2 : W1;
  float v = W[(size_t)l * DIM * DIM + (size_t)k * DIM + c];
  wt[((size_t)(l * 2 + mat) * DIM + c) * DIM + k] = (_Float16)v;
}

// ---------------- aggregation: agg[i] = sum_{j->i} T(P[j]);  T = relu(a*v+c) or identity ----------------
__global__ __launch_bounds__(256) void k_agg(const float* __restrict__ P, const int* __restrict__ rp,
                                             const int* __restrict__ es, const float* __restrict__ affine,
                                             float* __restrict__ agg, int use_aff) {
  int wid = (blockIdx.x * 256 + threadIdx.x) >> 6;   // wave per node
  int lane = threadIdx.x & 63;
  if (wid >= N_NODES) return;
  int e0 = rp[wid], e1 = rp[wid + 1];
  int c0 = lane * 2;
  float ax = 1.f, ay = 1.f, cx = 0.f, cy = 0.f;
  if (use_aff) {
    ax = affine[c0]; ay = affine[c0 + 1];
    cx = affine[DIM + c0]; cy = affine[DIM + c0 + 1];
  }
  float sx = 0.f, sy = 0.f;
  for (int e = e0; e < e1; ++e) {
    int s = es[e];
    float2 v = *(const float2*)(P + (size_t)s * DIM + c0);
    if (use_aff) {
      v.x = fmaxf(fmaf(ax, v.x, cx), 0.f);
      v.y = fmaxf(fmaf(ay, v.y, cy), 0.f);
    }
    sx += v.x; sy += v.y;
  }
  float2 r; r.x = sx; r.y = sy;
  *(float2*)(agg + (size_t)wid * DIM + c0) = r;
}

// ---------------- fused MLP: out = relu(x@W1+b1)@W2+b2,  x = T(P)+agg;  + BN stats ----------------
__global__ __launch_bounds__(256) void k_mlp(const float* __restrict__ P, const float* __restrict__ agg,
                                             const _Float16* __restrict__ wt,
                                             const float* __restrict__ b1, const float* __restrict__ b2,
                                             const float* __restrict__ affine,
                                             float* __restrict__ out, float* __restrict__ stats,
                                             int use_aff) {
  __shared__ _Float16 sh[16384 * 2 + 64 * DIM];   // w1t | w2t | tbuf = 80KB -> 2 blocks/CU
  _Float16* w1t = sh;
  _Float16* w2t = sh + 16384;
  _Float16* tb  = sh + 32768;

  const int tid = threadIdx.x;
  const int lane = tid & 63, w = tid >> 6;
  const int l15 = lane & 15, h = lane >> 4;

  // stage W1^T, W2^T to LDS (XOR-swizzled rows: kill ds_read_b128 bank conflicts)
  const half8* wg = (const half8*)wt;
#pragma unroll
  for (int i = 0; i < 16; ++i) {
    int h8 = i * 256 + tid;            // 0..4095
    half8 v = wg[h8];
    int idx8 = h8 & 2047;
    int c = idx8 >> 4, k8 = idx8 & 15;
    int hidx = (h8 >> 11) * 16384 + c * DIM + k8 * 8;
    hidx ^= ((c & 7) << 3);
    *(half8*)(sh + hidx) = v;
  }

  // build X fragments straight from global: x = T(P) + agg
  const int row = blockIdx.x * 64 + 16 * w + l15;
  const size_t rbase = (size_t)row * DIM;
  half8 xf[4];
#pragma unroll
  for (int kt = 0; kt < 4; ++kt) {
    int k0 = kt * 32 + 8 * h;
    float4 p0 = *(const float4*)(P + rbase + k0);
    float4 p1 = *(const float4*)(P + rbase + k0 + 4);
    float4 g0 = *(const float4*)(agg + rbase + k0);
    float4 g1 = *(const float4*)(agg + rbase + k0 + 4);
    float xs[8];
    if (use_aff) {
      float4 a0 = *(const float4*)(affine + k0);
      float4 a1 = *(const float4*)(affine + k0 + 4);
      float4 c0 = *(const float4*)(affine + DIM + k0);
      float4 c1 = *(const float4*)(affine + DIM + k0 + 4);
      xs[0] = fmaxf(fmaf(a0.x, p0.x, c0.x), 0.f) + g0.x;
      xs[1] = fmaxf(fmaf(a0.y, p0.y, c0.y), 0.f) + g0.y;
      xs[2] = fmaxf(fmaf(a0.z, p0.z, c0.z), 0.f) + g0.z;
      xs[3] = fmaxf(fmaf(a0.w, p0.w, c0.w), 0.f) + g0.w;
      xs[4] = fmaxf(fmaf(a1.x, p1.x, c1.x), 0.f) + g1.x;
      xs[5] = fmaxf(fmaf(a1.y, p1.y, c1.y), 0.f) + g1.y;
      xs[6] = fmaxf(fmaf(a1.z, p1.z, c1.z), 0.f) + g1.z;
      xs[7] = fmaxf(fmaf(a1.w, p1.w, c1.w), 0.f) + g1.w;
    } else {
      xs[0] = p0.x + g0.x; xs[1] = p0.y + g0.y; xs[2] = p0.z + g0.z; xs[3] = p0.w + g0.w;
      xs[4] = p1.x + g1.x; xs[5] = p1.y + g1.y; xs[6] = p1.z + g1.z; xs[7] = p1.w + g1.w;
    }
    half8 f;
#pragma unroll
    for (int j = 0; j < 8; ++j) f[j] = (_Float16)xs[j];
    xf[kt] = f;
  }
  __syncthreads();   // W tiles staged

  // GEMM1: t = relu(x @ W1 + b1) -> tbuf (fp16, swizzled)
#pragma unroll
  for (int ct = 0; ct < 8; ++ct) {
    int n = ct * 16 + l15;
    float bv = b1[n];
    f32x4 acc = {bv, bv, bv, bv};
#pragma unroll
    for (int kt = 0; kt < 4; ++kt) {
      int hidx = n * DIM + kt * 32 + 8 * h;
      hidx ^= ((n & 7) << 3);
      half8 bf = *(const half8*)(w1t + hidx);
      acc = __builtin_amdgcn_mfma_f32_16x16x32_f16(xf[kt], bf, acc, 0, 0, 0);
    }
#pragma unroll
    for (int r = 0; r < 4; ++r) {
      int lr = 16 * w + 4 * h + r;
      int ti = lr * DIM + n;
      ti ^= ((lr & 7) << 3);
      tb[ti] = (_Float16)fmaxf(acc[r], 0.f);
    }
  }
  __syncthreads();           // tbuf complete; w1t dead
  float* sst = (float*)sh;   // reuse w1t region for block stats
  sst[tid] = 0.f;
  __syncthreads();

  // GEMM2: y = t @ W2 + b2 -> out + stats
  half8 tf[4];
#pragma unroll
  for (int kt = 0; kt < 4; ++kt) {
    int lr = 16 * w + l15;
    int ti = lr * DIM + kt * 32 + 8 * h;
    ti ^= ((lr & 7) << 3);
    tf[kt] = *(const half8*)(tb + ti);
  }
  float sa[8], qa[8];
#pragma unroll
  for (int ct = 0; ct < 8; ++ct) {
    int n = ct * 16 + l15;
    float bv = b2[n];
    f32x4 acc = {bv, bv, bv, bv};
#pragma unroll
    for (int kt = 0; kt < 4; ++kt) {
      int hidx = n * DIM + kt * 32 + 8 * h;
      hidx ^= ((n & 7) << 3);
      half8 bf = *(const half8*)(w2t + hidx);
      acc = __builtin_amdgcn_mfma_f32_16x16x32_f16(tf[kt], bf, acc, 0, 0, 0);
    }
    float s = 0.f, q = 0.f;
#pragma unroll
    for (int r = 0; r < 4; ++r) {
      int grow = blockIdx.x * 64 + 16 * w + 4 * h + r;
      float y = acc[r];
      out[(size_t)grow * DIM + n] = y;
      s += y; q += y * y;
    }
    sa[ct] = s; qa[ct] = q;
  }
  // reduce stats: shfl across h-groups -> LDS -> sliced global atomics
#pragma unroll
  for (int ct = 0; ct < 8; ++ct) {
    float s = sa[ct], q = qa[ct];
    s += __shfl_xor(s, 16); s += __shfl_xor(s, 32);
    q += __shfl_xor(q, 16); q += __shfl_xor(q, 32);
    if (h == 0) {
      int n = ct * 16 + l15;
      atomicAdd(&sst[n], s);
      atomicAdd(&sst[DIM + n], q);
    }
  }
  __syncthreads();
  atomicAdd(&stats[(blockIdx.x & 63) * 256 + tid], sst[tid]);
}

// ---------------- finalize BN -> affine a,c ----------------
__global__ __launch_bounds__(128) void k_fin(const float* __restrict__ stats, const float* __restrict__ gamma,
                                             const float* __restrict__ beta, float* __restrict__ affine) {
  int c = threadIdx.x;   // 128
  float s = 0.f, q = 0.f;
  for (int i = 0; i < 64; ++i) {
    s += stats[i * 256 + c];
    q += stats[i * 256 + DIM + c];
  }
  float mean = s / (float)N_NODES;
  float var = q / (float)N_NODES - mean * mean;
  float inv = 1.f / sqrtf(var + BN_EPS);
  float a = gamma[c] * inv;
  affine[c] = a;
  affine[DIM + c] = beta[c] - mean * a;
}

// ---------------- final: out = a*z + c (no relu) ----------------
__global__ __launch_bounds__(256) void k_out(const float* __restrict__ z, const float* __restrict__ affine,
                                             float* __restrict__ out) {
  int idx = blockIdx.x * 256 + threadIdx.x;   // float4 index
  int c4 = (idx & 31) * 4;
  float4 v = *(const float4*)(z + (size_t)idx * 4);
  float4 a = *(const float4*)(affine + c4);
  float4 c = *(const float4*)(affine + DIM + c4);
  float4 r;
  r.x = fmaf(a.x, v.x, c.x); r.y = fmaf(a.y, v.y, c.y);
  r.z = fmaf(a.z, v.z, c.z); r.w = fmaf(a.w, v.w, c.w);
  *(float4*)(out + (size_t)idx * 4) = r;
}

extern "C" void kernel_launch(void* const* d_in, const int* in_sizes, int n_in,
                              void* d_out, int out_size, void* d_ws, size_t ws_size,
                              hipStream_t stream) {
  const int*   x     = (const int*)d_in[0];
  const int*   ei    = (const int*)d_in[1];
  // d_in[2] = edge_attr: unused by the reference
  const float* ea    = (const float*)d_in[3];
  const float* ec    = (const float*)d_in[4];
  const float* W1    = (const float*)d_in[5];
  const float* b1    = (const float*)d_in[6];
  const float* W2    = (const float*)d_in[7];
  const float* b2    = (const float*)d_in[8];
  const float* gamma = (const float*)d_in[9];
  const float* beta  = (const float*)d_in[10];
  const int* src = ei;
  const int* dst = ei + N_EDGES;

  char* ws = (char*)d_ws;
  size_t off = 0;
  auto take = [&](size_t b) { char* p = ws + off; off += (b + 255) & ~(size_t)255; return p; };
  float*    bufA   = (float*)take((size_t)N_NODES * DIM * 4);
  float*    bufB   = (float*)take((size_t)N_NODES * DIM * 4);
  float*    agg    = (float*)take((size_t)N_NODES * DIM * 4);
  _Float16* wt     = (_Float16*)take((size_t)NLAYER * 2 * DIM * DIM * 2);
  int*      rp     = (int*)take((size_t)(N_NODES + 1) * 4);
  int*      fill   = (int*)take((size_t)N_NODES * 4);
  int*      es     = (int*)take((size_t)N_EDGES * 4);
  int*      part   = (int*)take(4096);
  float*    stats  = (float*)take(64 * 256 * 4);
  float*    affine = (float*)take(256 * 4);
  if (off > ws_size) return;   // workspace too small -> fail loudly via wrong output

  const int NB1 = (N_NODES + 1023) / 1024;   // 391

  // CSR build (once per launch; reused across all 5 layers)
  hipMemsetAsync(fill, 0, (size_t)N_NODES * 4, stream);
  k_hist<<<(N_EDGES + 255) / 256, 256, 0, stream>>>(dst, fill);
  k_scan1<<<NB1, 256, 0, stream>>>(fill, rp, part);
  k_scan2<<<1, 512, 0, stream>>>(part, NB1);
  k_scan3<<<(N_NODES + 255) / 256, 256, 0, stream>>>(rp, part);
  hipMemsetAsync(fill, 0, (size_t)N_NODES * 4, stream);
  k_scatter<<<(N_EDGES + 255) / 256, 256, 0, stream>>>(src, dst, rp, fill, es);

  k_embed<<<N_NODES * 32 / 256, 256, 0, stream>>>(x, ea, ec, bufA);
  k_wprep<<<NLAYER * 2 * DIM, DIM, 0, stream>>>(W1, W2, wt);

  float* pin = bufA;
  float* pout = bufB;
  for (int l = 0; l < NLAYER; ++l) {
    int ua = (l > 0);
    k_agg<<<N_NODES * 64 / 256, 256, 0, stream>>>(pin, rp, es, affine, agg, ua);
    hipMemsetAsync(stats, 0, 64 * 256 * 4, stream);
    k_mlp<<<N_NODES / 64, 256, 0, stream>>>(pin, agg, wt + (size_t)l * 2 * DIM * DIM,
                                            b1 + l * DIM, b2 + l * DIM, affine, pout, stats, ua);
    k_fin<<<1, DIM, 0, stream>>>(stats, gamma + l * DIM, beta + l * DIM, affine);
    float* t = pin; pin = pout; pout = t;
  }
  k_out<<<N_NODES * 32 / 256, 256, 0, stream>>>(pin, affine, (float*)d_out);
}

// Round 10
// 1250.079 us; speedup vs baseline: 1.7376x; 1.7376x over previous
//
#include <hip/hip_runtime.h>
#include <hip/hip_bf16.h>

#define N_NODES 400000
#define N_EDGES 800000
#define DIM 128
#define NLAYER 5
#define BN_EPS 1e-5f

typedef _Float16 half8 __attribute__((ext_vector_type(8)));
typedef _Float16 half4 __attribute__((ext_vector_type(4)));
typedef _Float16 half2v __attribute__((ext_vector_type(2)));
typedef float f32x4 __attribute__((ext_vector_type(4)));

// ---------------- embedding: h0 = emb_atom[x0] + emb_chir[x1] (fp16 out) ----------------
__global__ __launch_bounds__(256) void k_embed(const int* __restrict__ x,
                                               const float* __restrict__ ea,
                                               const float* __restrict__ ec,
                                               _Float16* __restrict__ out) {
  int idx = blockIdx.x * 256 + threadIdx.x;      // 8-col chunk
  int i = idx >> 4, c8 = (idx & 15) * 8;
  int av = x[2 * i], cv = x[2 * i + 1];
  float4 a0 = *(const float4*)(ea + (size_t)av * DIM + c8);
  float4 a1 = *(const float4*)(ea + (size_t)av * DIM + c8 + 4);
  float4 c0 = *(const float4*)(ec + (size_t)cv * DIM + c8);
  float4 c1 = *(const float4*)(ec + (size_t)cv * DIM + c8 + 4);
  half8 r;
  r[0] = (_Float16)(a0.x + c0.x); r[1] = (_Float16)(a0.y + c0.y);
  r[2] = (_Float16)(a0.z + c0.z); r[3] = (_Float16)(a0.w + c0.w);
  r[4] = (_Float16)(a1.x + c1.x); r[5] = (_Float16)(a1.y + c1.y);
  r[6] = (_Float16)(a1.z + c1.z); r[7] = (_Float16)(a1.w + c1.w);
  *(half8*)(out + (size_t)i * DIM + c8) = r;
}

// ---------------- CSR build ----------------
__global__ __launch_bounds__(256) void k_hist(const int* __restrict__ dst, int* __restrict__ cnt) {
  int e = blockIdx.x * 256 + threadIdx.x;
  if (e < N_EDGES) atomicAdd(&cnt[dst[e]], 1);
}

__global__ __launch_bounds__(256) void k_scan1(const int* __restrict__ cnt, int* __restrict__ rp,
                                               int* __restrict__ part) {
  __shared__ int sm[256];
  int t = threadIdx.x;
  int base = blockIdx.x * 1024 + t * 4;
  int v0 = 0, v1 = 0, v2 = 0, v3 = 0;
  if (base + 4 <= N_NODES) {
    int4 v = *(const int4*)(cnt + base);
    v0 = v.x; v1 = v.y; v2 = v.z; v3 = v.w;
  } else {
    if (base     < N_NODES) v0 = cnt[base];
    if (base + 1 < N_NODES) v1 = cnt[base + 1];
    if (base + 2 < N_NODES) v2 = cnt[base + 2];
    if (base + 3 < N_NODES) v3 = cnt[base + 3];
  }
  int s = v0 + v1 + v2 + v3;
  sm[t] = s;
  __syncthreads();
  for (int off = 1; off < 256; off <<= 1) {
    int add = (t >= off) ? sm[t - off] : 0;
    __syncthreads();
    sm[t] += add;
    __syncthreads();
  }
  int incl = sm[t];
  int ex = incl - s;
  if (t == 255) part[blockIdx.x] = incl;
  if (base     < N_NODES) rp[base]     = ex;
  if (base + 1 < N_NODES) rp[base + 1] = ex + v0;
  if (base + 2 < N_NODES) rp[base + 2] = ex + v0 + v1;
  if (base + 3 < N_NODES) rp[base + 3] = ex + v0 + v1 + v2;
}

__global__ __launch_bounds__(512) void k_scan2(int* __restrict__ part, int nb) {
  __shared__ int sm[512];
  int t = threadIdx.x;
  int v = (t < nb) ? part[t] : 0;
  sm[t] = v;
  __syncthreads();
  for (int off = 1; off < 512; off <<= 1) {
    int add = (t >= off) ? sm[t - off] : 0;
    __syncthreads();
    sm[t] += add;
    __syncthreads();
  }
  if (t < nb) part[t] = sm[t] - v;   // exclusive
}

__global__ __launch_bounds__(256) void k_scan3(int* __restrict__ rp, const int* __restrict__ part) {
  int i = blockIdx.x * 256 + threadIdx.x;
  if (i < N_NODES) rp[i] += part[i >> 10];
  if (i == 0) rp[N_NODES] = N_EDGES;
}

__global__ __launch_bounds__(256) void k_scatter(const int* __restrict__ src, const int* __restrict__ dst,
                                                 const int* __restrict__ rp, int* __restrict__ fill,
                                                 int* __restrict__ es) {
  int e = blockIdx.x * 256 + threadIdx.x;
  if (e < N_EDGES) {
    int d = dst[e];
    int slot = rp[d] + atomicAdd(&fill[d], 1);
    es[slot] = src[e];
  }
}

// ---------------- W pre-transpose to fp16: wt[l][mat][c][k] = W[l][k][c] ----------------
__global__ __launch_bounds__(128) void k_wprep(const float* __restrict__ W1, const float* __restrict__ W2,
                                               _Float16* __restrict__ wt) {
  int b = blockIdx.x;                 // 5*2*128
  int l = b >> 8, mat = (b >> 7) & 1, c = b & 127;
  int k = threadIdx.x;                // 128
  const float* W = mat ? W2 : W1;
  float v = W[(size_t)l * DIM * DIM + (size_t)k * DIM + c];
  wt[((size_t)(l * 2 + mat) * DIM + c) * DIM + k] = (_Float16)v;
}

// ---------------- X build: X[i] = T(P[i]) + sum_{j->i} T(P[j]);  T = relu(a*v+c) or identity
// 4 nodes per wave: 16-lane group per node, half8 (8 cols) per lane -> 256B coalesced row gathers,
// 4 independent latency chains per wave (x2 with unroll-2 dual accumulators).
template <int UA>
__global__ __launch_bounds__(256) void k_aggx(const _Float16* __restrict__ P, const int* __restrict__ rp,
                                              const int* __restrict__ es, const float* __restrict__ affine,
                                              _Float16* __restrict__ X) {
  const int lane = threadIdx.x & 63;
  const int g = lane >> 4, gl = lane & 15;
  const int wid = (blockIdx.x * 256 + threadIdx.x) >> 6;   // 0..99999
  const int nid = wid * 4 + g;                             // 0..399999
  const int c8 = gl * 8;

  float a[8], c[8];
  if (UA) {
    float4 t0 = *(const float4*)(affine + c8);
    float4 t1 = *(const float4*)(affine + c8 + 4);
    float4 u0 = *(const float4*)(affine + DIM + c8);
    float4 u1 = *(const float4*)(affine + DIM + c8 + 4);
    a[0] = t0.x; a[1] = t0.y; a[2] = t0.z; a[3] = t0.w;
    a[4] = t1.x; a[5] = t1.y; a[6] = t1.z; a[7] = t1.w;
    c[0] = u0.x; c[1] = u0.y; c[2] = u0.z; c[3] = u0.w;
    c[4] = u1.x; c[5] = u1.y; c[6] = u1.z; c[7] = u1.w;
  }
  const int e0 = rp[nid], e1 = rp[nid + 1];

  half8 sv = *(const half8*)(P + (size_t)nid * DIM + c8);
  float sx[8], tx[8];
#pragma unroll
  for (int i = 0; i < 8; ++i) {
    float v = (float)sv[i];
    sx[i] = UA ? fmaxf(fmaf(a[i], v, c[i]), 0.f) : v;
    tx[i] = 0.f;
  }
  for (int base = e0; base < e1; base += 16) {
    int n = e1 - base; if (n > 16) n = 16;
    int esr = (base + gl < e1) ? es[base + gl] : 0;   // group-parallel index prefetch
    int j = 0;
    for (; j + 2 <= n; j += 2) {                      // unroll-2: two gathers in flight
      int s0 = __shfl(esr, (g << 4) + j);
      int s1 = __shfl(esr, (g << 4) + j + 1);
      half8 v0 = *(const half8*)(P + (size_t)s0 * DIM + c8);
      half8 v1 = *(const half8*)(P + (size_t)s1 * DIM + c8);
#pragma unroll
      for (int i = 0; i < 8; ++i) {
        float f0 = (float)v0[i], f1 = (float)v1[i];
        if (UA) {
          f0 = fmaxf(fmaf(a[i], f0, c[i]), 0.f);
          f1 = fmaxf(fmaf(a[i], f1, c[i]), 0.f);
        }
        sx[i] += f0; tx[i] += f1;
      }
    }
    if (j < n) {
      int s0 = __shfl(esr, (g << 4) + j);
      half8 v0 = *(const half8*)(P + (size_t)s0 * DIM + c8);
#pragma unroll
      for (int i = 0; i < 8; ++i) {
        float f0 = (float)v0[i];
        if (UA) f0 = fmaxf(fmaf(a[i], f0, c[i]), 0.f);
        sx[i] += f0;
      }
    }
  }
  half8 r;
#pragma unroll
  for (int i = 0; i < 8; ++i) r[i] = (_Float16)(sx[i] + tx[i]);
  *(half8*)(X + (size_t)nid * DIM + c8) = r;
}

// ---------------- fused MLP: Z = relu(X@W1+b1)@W2+b2 (fp16 out) + BN stats ----------------
__global__ __launch_bounds__(256) void k_mlp(const _Float16* __restrict__ X,
                                             const _Float16* __restrict__ wt,
                                             const float* __restrict__ b1, const float* __restrict__ b2,
                                             _Float16* __restrict__ Z, float* __restrict__ stats) {
  __shared__ _Float16 sh[16384 * 2 + 64 * DIM];   // w1t | w2t | tbuf = 80KB -> 2 blocks/CU
  _Float16* w1t = sh;
  _Float16* w2t = sh + 16384;
  _Float16* tb  = sh + 32768;

  const int tid = threadIdx.x;
  const int lane = tid & 63, w = tid >> 6;
  const int l15 = lane & 15, h = lane >> 4;

  // stage W1^T, W2^T to LDS (XOR-swizzled rows)
  const half8* wg = (const half8*)wt;
#pragma unroll
  for (int i = 0; i < 16; ++i) {
    int h8 = i * 256 + tid;            // 0..4095
    half8 v = wg[h8];
    int idx8 = h8 & 2047;
    int c = idx8 >> 4, k8 = idx8 & 15;
    int hidx = (h8 >> 11) * 16384 + c * DIM + k8 * 8;
    hidx ^= ((c & 7) << 3);
    *(half8*)(sh + hidx) = v;
  }

  // X fragments straight from global (already fp16, MFMA-ready)
  const int row = blockIdx.x * 64 + 16 * w + l15;
  const size_t rbase = (size_t)row * DIM;
  half8 xf[4];
#pragma unroll
  for (int kt = 0; kt < 4; ++kt)
    xf[kt] = *(const half8*)(X + rbase + kt * 32 + 8 * h);
  __syncthreads();   // W tiles staged

  // GEMM1: t = relu(x @ W1 + b1) -> tbuf (fp16, swizzled)
#pragma unroll
  for (int ct = 0; ct < 8; ++ct) {
    int n = ct * 16 + l15;
    float bv = b1[n];
    f32x4 acc = {bv, bv, bv, bv};
#pragma unroll
    for (int kt = 0; kt < 4; ++kt) {
      int hidx = n * DIM + kt * 32 + 8 * h;
      hidx ^= ((n & 7) << 3);
      half8 bf = *(const half8*)(w1t + hidx);
      acc = __builtin_amdgcn_mfma_f32_16x16x32_f16(xf[kt], bf, acc, 0, 0, 0);
    }
#pragma unroll
    for (int r = 0; r < 4; ++r) {
      int lr = 16 * w + 4 * h + r;
      int ti = lr * DIM + n;
      ti ^= ((lr & 7) << 3);
      tb[ti] = (_Float16)fmaxf(acc[r], 0.f);
    }
  }
  __syncthreads();           // tbuf complete; w1t dead

  // load t fragments for GEMM2
  half8 tf[4];
#pragma unroll
  for (int kt = 0; kt < 4; ++kt) {
    int lr = 16 * w + l15;
    int ti = lr * DIM + kt * 32 + 8 * h;
    ti ^= ((lr & 7) << 3);
    tf[kt] = *(const half8*)(tb + ti);
  }
  float* sst = (float*)sh;   // reuse w1t region for block stats
  sst[tid] = 0.f;
  __syncthreads();           // all tf loaded; tb reusable for z

  // GEMM2: z = t @ W2 + b2 -> tb (fp16) + stats
  float sa[8], qa[8];
#pragma unroll
  for (int ct = 0; ct < 8; ++ct) {
    int n = ct * 16 + l15;
    float bv = b2[n];
    f32x4 acc = {bv, bv, bv, bv};
#pragma unroll
    for (int kt = 0; kt < 4; ++kt) {
      int hidx = n * DIM + kt * 32 + 8 * h;
      hidx ^= ((n & 7) << 3);
      half8 bf = *(const half8*)(w2t + hidx);
      acc = __builtin_amdgcn_mfma_f32_16x16x32_f16(tf[kt], bf, acc, 0, 0, 0);
    }
    float s = 0.f, q = 0.f;
#pragma unroll
    for (int r = 0; r < 4; ++r) {
      int lr = 16 * w + 4 * h + r;
      float y = acc[r];
      int ti = lr * DIM + n;
      ti ^= ((lr & 7) << 3);
      tb[ti] = (_Float16)y;
      s += y; q += y * y;
    }
    sa[ct] = s; qa[ct] = q;
  }
  // reduce stats: shfl across h-groups -> LDS -> sliced global atomics
#pragma unroll
  for (int ct = 0; ct < 8; ++ct) {
    float s = sa[ct], q = qa[ct];
    s += __shfl_xor(s, 16); s += __shfl_xor(s, 32);
    q += __shfl_xor(q, 16); q += __shfl_xor(q, 32);
    if (h == 0) {
      int n = ct * 16 + l15;
      atomicAdd(&sst[n], s);
      atomicAdd(&sst[DIM + n], q);
    }
  }
  __syncthreads();           // z tile + sst complete

  // coalesced fp16 row stores from tb
#pragma unroll
  for (int i = 0; i < 4; ++i) {
    int chunk = i * 256 + tid;         // 0..1023
    int lr = chunk >> 4, k8 = chunk & 15;
    int ti = (lr * DIM + k8 * 8) ^ ((lr & 7) << 3);
    half8 v = *(const half8*)(tb + ti);
    *(half8*)(Z + (size_t)(blockIdx.x * 64 + lr) * DIM + k8 * 8) = v;
  }
  atomicAdd(&stats[(blockIdx.x & 63) * 256 + tid], sst[tid]);
}

// ---------------- finalize BN -> affine a,c ----------------
__global__ __launch_bounds__(128) void k_fin(const float* __restrict__ stats, const float* __restrict__ gamma,
                                             const float* __restrict__ beta, float* __restrict__ affine) {
  int c = threadIdx.x;   // 128
  float s = 0.f, q = 0.f;
  for (int i = 0; i < 64; ++i) {
    s += stats[i * 256 + c];
    q += stats[i * 256 + DIM + c];
  }
  float mean = s / (float)N_NODES;
  float var = q / (float)N_NODES - mean * mean;
  float inv = 1.f / sqrtf(var + BN_EPS);
  float a = gamma[c] * inv;
  affine[c] = a;
  affine[DIM + c] = beta[c] - mean * a;
}

// ---------------- final: out = a*z + c (no relu), fp32 out ----------------
__global__ __launch_bounds__(256) void k_out(const _Float16* __restrict__ z, const float* __restrict__ affine,
                                             float* __restrict__ out) {
  int idx = blockIdx.x * 256 + threadIdx.x;   // 4-col chunk
  int c4 = (idx & 31) * 4;
  half4 v = *(const half4*)(z + (size_t)idx * 4);
  float4 a = *(const float4*)(affine + c4);
  float4 c = *(const float4*)(affine + DIM + c4);
  float4 r;
  r.x = fmaf(a.x, (float)v[0], c.x); r.y = fmaf(a.y, (float)v[1], c.y);
  r.z = fmaf(a.z, (float)v[2], c.z); r.w = fmaf(a.w, (float)v[3], c.w);
  *(float4*)(out + (size_t)idx * 4) = r;
}

extern "C" void kernel_launch(void* const* d_in, const int* in_sizes, int n_in,
                              void* d_out, int out_size, void* d_ws, size_t ws_size,
                              hipStream_t stream) {
  const int*   x     = (const int*)d_in[0];
  const int*   ei    = (const int*)d_in[1];
  // d_in[2] = edge_attr: unused by the reference
  const float* ea    = (const float*)d_in[3];
  const float* ec    = (const float*)d_in[4];
  const float* W1    = (const float*)d_in[5];
  const float* b1    = (const float*)d_in[6];
  const float* W2    = (const float*)d_in[7];
  const float* b2    = (const float*)d_in[8];
  const float* gamma = (const float*)d_in[9];
  const float* beta  = (const float*)d_in[10];
  const int* src = ei;
  const int* dst = ei + N_EDGES;

  char* ws = (char*)d_ws;
  size_t off = 0;
  auto take = [&](size_t b) { char* p = ws + off; off += (b + 255) & ~(size_t)255; return p; };
  _Float16* Z0     = (_Float16*)take((size_t)N_NODES * DIM * 2);
  _Float16* Z1     = (_Float16*)take((size_t)N_NODES * DIM * 2);
  _Float16* X      = (_Float16*)take((size_t)N_NODES * DIM * 2);
  _Float16* wt     = (_Float16*)take((size_t)NLAYER * 2 * DIM * DIM * 2);
  int*      rp     = (int*)take((size_t)(N_NODES + 1) * 4);
  int*      fill   = (int*)take((size_t)N_NODES * 4);
  int*      es     = (int*)take((size_t)N_EDGES * 4);
  int*      part   = (int*)take(4096);
  float*    stats  = (float*)take(64 * 256 * 4);
  float*    affine = (float*)take(256 * 4);
  if (off > ws_size) return;

  const int NB1 = (N_NODES + 1023) / 1024;   // 391

  // CSR build (once per launch; reused across all 5 layers)
  hipMemsetAsync(fill, 0, (size_t)N_NODES * 4, stream);
  k_hist<<<(N_EDGES + 255) / 256, 256, 0, stream>>>(dst, fill);
  k_scan1<<<NB1, 256, 0, stream>>>(fill, rp, part);
  k_scan2<<<1, 512, 0, stream>>>(part, NB1);
  k_scan3<<<(N_NODES + 255) / 256, 256, 0, stream>>>(rp, part);
  hipMemsetAsync(fill, 0, (size_t)N_NODES * 4, stream);
  k_scatter<<<(N_EDGES + 255) / 256, 256, 0, stream>>>(src, dst, rp, fill, es);

  k_embed<<<N_NODES * 16 / 256, 256, 0, stream>>>(x, ea, ec, Z0);
  k_wprep<<<NLAYER * 2 * DIM, DIM, 0, stream>>>(W1, W2, wt);

  _Float16* pin = Z0;
  _Float16* pout = Z1;
  for (int l = 0; l < NLAYER; ++l) {
    if (l == 0)
      k_aggx<0><<<N_NODES / 16, 256, 0, stream>>>(pin, rp, es, affine, X);
    else
      k_aggx<1><<<N_NODES / 16, 256, 0, stream>>>(pin, rp, es, affine, X);
    hipMemsetAsync(stats, 0, 64 * 256 * 4, stream);
    k_mlp<<<N_NODES / 64, 256, 0, stream>>>(X, wt + (size_t)l * 2 * DIM * DIM,
                                            b1 + l * DIM, b2 + l * DIM, pout, stats);
    k_fin<<<1, DIM, 0, stream>>>(stats, gamma + l * DIM, beta + l * DIM, affine);
    _Float16* t = pin; pin = pout; pout = t;
  }
  k_out<<<N_NODES * 32 / 256, 256, 0, stream>>>(pin, affine, (float*)d_out);
}

// Round 11
// 1188.875 us; speedup vs baseline: 1.8270x; 1.0515x over previous
//
#include <hip/hip_runtime.h>
#include <hip/hip_bf16.h>

#define N_NODES 400000
#define N_EDGES 800000
#define DIM 128
#define NLAYER 5
#define BN_EPS 1e-5f

typedef _Float16 half8 __attribute__((ext_vector_type(8)));
typedef _Float16 half4 __attribute__((ext_vector_type(4)));
typedef float f32x4 __attribute__((ext_vector_type(4)));

// ---------------- embedding: h0 = emb_atom[x0] + emb_chir[x1] (fp16 out) ----------------
__global__ __launch_bounds__(256) void k_embed(const int* __restrict__ x,
                                               const float* __restrict__ ea,
                                               const float* __restrict__ ec,
                                               _Float16* __restrict__ out) {
  int idx = blockIdx.x * 256 + threadIdx.x;      // 8-col chunk
  int i = idx >> 4, c8 = (idx & 15) * 8;
  int av = x[2 * i], cv = x[2 * i + 1];
  float4 a0 = *(const float4*)(ea + (size_t)av * DIM + c8);
  float4 a1 = *(const float4*)(ea + (size_t)av * DIM + c8 + 4);
  float4 c0 = *(const float4*)(ec + (size_t)cv * DIM + c8);
  float4 c1 = *(const float4*)(ec + (size_t)cv * DIM + c8 + 4);
  half8 r;
  r[0] = (_Float16)(a0.x + c0.x); r[1] = (_Float16)(a0.y + c0.y);
  r[2] = (_Float16)(a0.z + c0.z); r[3] = (_Float16)(a0.w + c0.w);
  r[4] = (_Float16)(a1.x + c1.x); r[5] = (_Float16)(a1.y + c1.y);
  r[6] = (_Float16)(a1.z + c1.z); r[7] = (_Float16)(a1.w + c1.w);
  *(half8*)(out + (size_t)i * DIM + c8) = r;
}

// ---------------- CSR build ----------------
__global__ __launch_bounds__(256) void k_hist(const int* __restrict__ dst, int* __restrict__ cnt) {
  int e = blockIdx.x * 256 + threadIdx.x;
  if (e < N_EDGES) atomicAdd(&cnt[dst[e]], 1);
}

__global__ __launch_bounds__(256) void k_scan1(const int* __restrict__ cnt, int* __restrict__ rp,
                                               int* __restrict__ part) {
  __shared__ int sm[256];
  int t = threadIdx.x;
  int base = blockIdx.x * 1024 + t * 4;
  int v0 = 0, v1 = 0, v2 = 0, v3 = 0;
  if (base + 4 <= N_NODES) {
    int4 v = *(const int4*)(cnt + base);
    v0 = v.x; v1 = v.y; v2 = v.z; v3 = v.w;
  } else {
    if (base     < N_NODES) v0 = cnt[base];
    if (base + 1 < N_NODES) v1 = cnt[base + 1];
    if (base + 2 < N_NODES) v2 = cnt[base + 2];
    if (base + 3 < N_NODES) v3 = cnt[base + 3];
  }
  int s = v0 + v1 + v2 + v3;
  sm[t] = s;
  __syncthreads();
  for (int off = 1; off < 256; off <<= 1) {
    int add = (t >= off) ? sm[t - off] : 0;
    __syncthreads();
    sm[t] += add;
    __syncthreads();
  }
  int incl = sm[t];
  int ex = incl - s;
  if (t == 255) part[blockIdx.x] = incl;
  if (base     < N_NODES) rp[base]     = ex;
  if (base + 1 < N_NODES) rp[base + 1] = ex + v0;
  if (base + 2 < N_NODES) rp[base + 2] = ex + v0 + v1;
  if (base + 3 < N_NODES) rp[base + 3] = ex + v0 + v1 + v2;
}

__global__ __launch_bounds__(512) void k_scan2(int* __restrict__ part, int nb) {
  __shared__ int sm[512];
  int t = threadIdx.x;
  int v = (t < nb) ? part[t] : 0;
  sm[t] = v;
  __syncthreads();
  for (int off = 1; off < 512; off <<= 1) {
    int add = (t >= off) ? sm[t - off] : 0;
    __syncthreads();
    sm[t] += add;
    __syncthreads();
  }
  if (t < nb) part[t] = sm[t] - v;   // exclusive
}

__global__ __launch_bounds__(256) void k_scan3(int* __restrict__ rp, const int* __restrict__ part) {
  int i = blockIdx.x * 256 + threadIdx.x;
  if (i < N_NODES) rp[i] += part[i >> 10];
  if (i == 0) rp[N_NODES] = N_EDGES;
}

__global__ __launch_bounds__(256) void k_scatter(const int* __restrict__ src, const int* __restrict__ dst,
                                                 const int* __restrict__ rp, int* __restrict__ fill,
                                                 int* __restrict__ es) {
  int e = blockIdx.x * 256 + threadIdx.x;
  if (e < N_EDGES) {
    int d = dst[e];
    int slot = rp[d] + atomicAdd(&fill[d], 1);
    es[slot] = src[e];
  }
}

// ---------------- W pre-transpose to fp16: wt[l][mat][c][k] = W[l][k][c] ----------------
__global__ __launch_bounds__(128) void k_wprep(const float* __restrict__ W1, const float* __restrict__ W2,
                                               _Float16* __restrict__ wt) {
  int b = blockIdx.x;                 // 5*2*128
  int l = b >> 8, mat = (b >> 7) & 1, c = b & 127;
  int k = threadIdx.x;                // 128
  const float* W = mat ? W2 : W1;
  float v = W[(size_t)l * DIM * DIM + (size_t)k * DIM + c];
  wt[((size_t)(l * 2 + mat) * DIM + c) * DIM + k] = (_Float16)v;
}

// ---------------- X build: X[i] = T(P[i]) + sum_{j->i} T(P[j]);  T = relu(a*v+c) or identity
// 4 nodes per wave (16-lane group per node, half8/lane = 256B coalesced row gather).
// Quad-gather: 4 concurrent row loads per group with 0/1 weights -> serial depth = rp->es->1 gather RT.
template <int UA>
__global__ __launch_bounds__(256) void k_aggx(const _Float16* __restrict__ P, const int* __restrict__ rp,
                                              const int* __restrict__ es, const float* __restrict__ affine,
                                              _Float16* __restrict__ X) {
  const int lane = threadIdx.x & 63;
  const int g = lane >> 4, gl = lane & 15;
  const int wid = (blockIdx.x * 256 + threadIdx.x) >> 6;   // 0..99999
  const int nid = wid * 4 + g;                             // 0..399999
  const int c8 = gl * 8;

  float a[8], c[8];
  if (UA) {
    float4 t0 = *(const float4*)(affine + c8);
    float4 t1 = *(const float4*)(affine + c8 + 4);
    float4 u0 = *(const float4*)(affine + DIM + c8);
    float4 u1 = *(const float4*)(affine + DIM + c8 + 4);
    a[0] = t0.x; a[1] = t0.y; a[2] = t0.z; a[3] = t0.w;
    a[4] = t1.x; a[5] = t1.y; a[6] = t1.z; a[7] = t1.w;
    c[0] = u0.x; c[1] = u0.y; c[2] = u0.z; c[3] = u0.w;
    c[4] = u1.x; c[5] = u1.y; c[6] = u1.z; c[7] = u1.w;
  }
  const int e0 = rp[nid], e1 = rp[nid + 1];

  half8 sv = *(const half8*)(P + (size_t)nid * DIM + c8);
  float sx[8];
#pragma unroll
  for (int i = 0; i < 8; ++i) {
    float v = (float)sv[i];
    sx[i] = UA ? fmaxf(fmaf(a[i], v, c[i]), 0.f) : v;
  }
  for (int base = e0; base < e1; base += 16) {
    int n = e1 - base; if (n > 16) n = 16;
    int esr = (base + gl < e1) ? es[base + gl] : 0;   // group-parallel index prefetch
    for (int j = 0; j < n; j += 4) {                  // quad: 4 gathers in flight
      int s0 = __shfl(esr, (g << 4) + j);
      int s1 = __shfl(esr, (g << 4) + j + 1);
      int s2 = __shfl(esr, (g << 4) + j + 2);
      int s3 = __shfl(esr, (g << 4) + j + 3);
      float w1 = (j + 1 < n) ? 1.f : 0.f;             // tail lanes hit row 0 (L1), weight 0
      float w2 = (j + 2 < n) ? 1.f : 0.f;
      float w3 = (j + 3 < n) ? 1.f : 0.f;
      half8 v0 = *(const half8*)(P + (size_t)s0 * DIM + c8);
      half8 v1 = *(const half8*)(P + (size_t)s1 * DIM + c8);
      half8 v2 = *(const half8*)(P + (size_t)s2 * DIM + c8);
      half8 v3 = *(const half8*)(P + (size_t)s3 * DIM + c8);
#pragma unroll
      for (int i = 0; i < 8; ++i) {
        float f0 = (float)v0[i], f1 = (float)v1[i];
        float f2 = (float)v2[i], f3 = (float)v3[i];
        if (UA) {
          f0 = fmaxf(fmaf(a[i], f0, c[i]), 0.f);
          f1 = fmaxf(fmaf(a[i], f1, c[i]), 0.f);
          f2 = fmaxf(fmaf(a[i], f2, c[i]), 0.f);
          f3 = fmaxf(fmaf(a[i], f3, c[i]), 0.f);
        }
        sx[i] += f0 + w1 * f1 + w2 * f2 + w3 * f3;
      }
    }
  }
  half8 r;
#pragma unroll
  for (int i = 0; i < 8; ++i) r[i] = (_Float16)sx[i];
  *(half8*)(X + (size_t)nid * DIM + c8) = r;
}

// ---------------- fused MLP: Z = relu(X@W1+b1)@W2+b2 (fp16 out) + BN stats
// 48KB LDS (one 32KB W buffer, staged twice) -> 3 blocks/CU (was 2 at 80KB).
__global__ __launch_bounds__(256) void k_mlp(const _Float16* __restrict__ X,
                                             const _Float16* __restrict__ wt,
                                             const float* __restrict__ b1, const float* __restrict__ b2,
                                             _Float16* __restrict__ Z, float* __restrict__ stats) {
  __shared__ _Float16 sh[16384 + 64 * DIM];   // wbuf (32KB) | tbuf (16KB) = 48KB
  _Float16* wbuf = sh;
  _Float16* tb   = sh + 16384;

  const int tid = threadIdx.x;
  const int lane = tid & 63, w = tid >> 6;
  const int l15 = lane & 15, h = lane >> 4;
  const half8* wg = (const half8*)wt;

  // stage W1^T to LDS (XOR-swizzled rows)
#pragma unroll
  for (int i = 0; i < 8; ++i) {
    int h8 = i * 256 + tid;            // 0..2047
    half8 v = wg[h8];
    int cc = h8 >> 4, k8 = h8 & 15;
    int hidx = (cc * DIM + k8 * 8) ^ ((cc & 7) << 3);
    *(half8*)(wbuf + hidx) = v;
  }

  // X fragments straight from global (already fp16, MFMA-ready)
  const int row = blockIdx.x * 64 + 16 * w + l15;
  const size_t rbase = (size_t)row * DIM;
  half8 xf[4];
#pragma unroll
  for (int kt = 0; kt < 4; ++kt)
    xf[kt] = *(const half8*)(X + rbase + kt * 32 + 8 * h);
  __syncthreads();   // W1 staged

  // GEMM1: t = relu(x @ W1 + b1) -> tbuf (fp16, swizzled)
#pragma unroll
  for (int ct = 0; ct < 8; ++ct) {
    int n = ct * 16 + l15;
    float bv = b1[n];
    f32x4 acc = {bv, bv, bv, bv};
#pragma unroll
    for (int kt = 0; kt < 4; ++kt) {
      int hidx = (n * DIM + kt * 32 + 8 * h) ^ ((n & 7) << 3);
      half8 bf = *(const half8*)(wbuf + hidx);
      acc = __builtin_amdgcn_mfma_f32_16x16x32_f16(xf[kt], bf, acc, 0, 0, 0);
    }
#pragma unroll
    for (int r = 0; r < 4; ++r) {
      int lr = 16 * w + 4 * h + r;
      int ti = (lr * DIM + n) ^ ((lr & 7) << 3);
      tb[ti] = (_Float16)fmaxf(acc[r], 0.f);
    }
  }
  __syncthreads();           // tbuf complete; wbuf (W1) dead

  // stage W2^T into the same buffer + load t fragments
#pragma unroll
  for (int i = 0; i < 8; ++i) {
    int h8 = 2048 + i * 256 + tid;     // W2 half8s
    half8 v = wg[h8];
    int idx8 = h8 & 2047;
    int cc = idx8 >> 4, k8 = idx8 & 15;
    int hidx = (cc * DIM + k8 * 8) ^ ((cc & 7) << 3);
    *(half8*)(wbuf + hidx) = v;
  }
  half8 tf[4];
#pragma unroll
  for (int kt = 0; kt < 4; ++kt) {
    int lr = 16 * w + l15;
    int ti = (lr * DIM + kt * 32 + 8 * h) ^ ((lr & 7) << 3);
    tf[kt] = *(const half8*)(tb + ti);
  }
  __syncthreads();           // W2 staged; all tf loaded -> tb reusable for z

  // GEMM2: z = t @ W2 + b2 -> tb (fp16) + stats in regs
  float sa[8], qa[8];
#pragma unroll
  for (int ct = 0; ct < 8; ++ct) {
    int n = ct * 16 + l15;
    float bv = b2[n];
    f32x4 acc = {bv, bv, bv, bv};
#pragma unroll
    for (int kt = 0; kt < 4; ++kt) {
      int hidx = (n * DIM + kt * 32 + 8 * h) ^ ((n & 7) << 3);
      half8 bf = *(const half8*)(wbuf + hidx);
      acc = __builtin_amdgcn_mfma_f32_16x16x32_f16(tf[kt], bf, acc, 0, 0, 0);
    }
    float s = 0.f, q = 0.f;
#pragma unroll
    for (int r = 0; r < 4; ++r) {
      int lr = 16 * w + 4 * h + r;
      float y = acc[r];
      int ti = (lr * DIM + n) ^ ((lr & 7) << 3);
      tb[ti] = (_Float16)y;
      s += y; q += y * y;
    }
    sa[ct] = s; qa[ct] = q;
  }
  __syncthreads();           // GEMM2 done; wbuf dead -> reuse for stats

  float* sst = (float*)sh;
  sst[tid] = 0.f;
  __syncthreads();
  // reduce stats: shfl across h-groups -> LDS -> sliced global atomics
#pragma unroll
  for (int ct = 0; ct < 8; ++ct) {
    float s = sa[ct], q = qa[ct];
    s += __shfl_xor(s, 16); s += __shfl_xor(s, 32);
    q += __shfl_xor(q, 16); q += __shfl_xor(q, 32);
    if (h == 0) {
      int n = ct * 16 + l15;
      atomicAdd(&sst[n], s);
      atomicAdd(&sst[DIM + n], q);
    }
  }
  __syncthreads();           // z tile + sst complete

  // coalesced fp16 row stores from tb
#pragma unroll
  for (int i = 0; i < 4; ++i) {
    int chunk = i * 256 + tid;         // 0..1023
    int lr = chunk >> 4, k8 = chunk & 15;
    int ti = (lr * DIM + k8 * 8) ^ ((lr & 7) << 3);
    half8 v = *(const half8*)(tb + ti);
    *(half8*)(Z + (size_t)(blockIdx.x * 64 + lr) * DIM + k8 * 8) = v;
  }
  atomicAdd(&stats[(blockIdx.x & 63) * 256 + tid], sst[tid]);
}

// ---------------- finalize BN -> affine a,c ----------------
__global__ __launch_bounds__(128) void k_fin(const float* __restrict__ stats, const float* __restrict__ gamma,
                                             const float* __restrict__ beta, float* __restrict__ affine) {
  int c = threadIdx.x;   // 128
  float s = 0.f, q = 0.f;
  for (int i = 0; i < 64; ++i) {
    s += stats[i * 256 + c];
    q += stats[i * 256 + DIM + c];
  }
  float mean = s / (float)N_NODES;
  float var = q / (float)N_NODES - mean * mean;
  float inv = 1.f / sqrtf(var + BN_EPS);
  float a = gamma[c] * inv;
  affine[c] = a;
  affine[DIM + c] = beta[c] - mean * a;
}

// ---------------- final: out = a*z + c (no relu), fp32 out ----------------
__global__ __launch_bounds__(256) void k_out(const _Float16* __restrict__ z, const float* __restrict__ affine,
                                             float* __restrict__ out) {
  int idx = blockIdx.x * 256 + threadIdx.x;   // 4-col chunk
  int c4 = (idx & 31) * 4;
  half4 v = *(const half4*)(z + (size_t)idx * 4);
  float4 a = *(const float4*)(affine + c4);
  float4 c = *(const float4*)(affine + DIM + c4);
  float4 r;
  r.x = fmaf(a.x, (float)v[0], c.x); r.y = fmaf(a.y, (float)v[1], c.y);
  r.z = fmaf(a.z, (float)v[2], c.z); r.w = fmaf(a.w, (float)v[3], c.w);
  *(float4*)(out + (size_t)idx * 4) = r;
}

extern "C" void kernel_launch(void* const* d_in, const int* in_sizes, int n_in,
                              void* d_out, int out_size, void* d_ws, size_t ws_size,
                              hipStream_t stream) {
  const int*   x     = (const int*)d_in[0];
  const int*   ei    = (const int*)d_in[1];
  // d_in[2] = edge_attr: unused by the reference
  const float* ea    = (const float*)d_in[3];
  const float* ec    = (const float*)d_in[4];
  const float* W1    = (const float*)d_in[5];
  const float* b1    = (const float*)d_in[6];
  const float* W2    = (const float*)d_in[7];
  const float* b2    = (const float*)d_in[8];
  const float* gamma = (const float*)d_in[9];
  const float* beta  = (const float*)d_in[10];
  const int* src = ei;
  const int* dst = ei + N_EDGES;

  char* ws = (char*)d_ws;
  size_t off = 0;
  auto take = [&](size_t b) { char* p = ws + off; off += (b + 255) & ~(size_t)255; return p; };
  _Float16* Z0     = (_Float16*)take((size_t)N_NODES * DIM * 2);
  _Float16* Z1     = (_Float16*)take((size_t)N_NODES * DIM * 2);
  _Float16* X      = (_Float16*)take((size_t)N_NODES * DIM * 2);
  _Float16* wt     = (_Float16*)take((size_t)NLAYER * 2 * DIM * DIM * 2);
  int*      rp     = (int*)take((size_t)(N_NODES + 1) * 4);
  int*      fill   = (int*)take((size_t)N_NODES * 4);
  int*      es     = (int*)take((size_t)N_EDGES * 4);
  int*      part   = (int*)take(4096);
  float*    stats  = (float*)take(64 * 256 * 4);
  float*    affine = (float*)take(256 * 4);
  if (off > ws_size) return;

  const int NB1 = (N_NODES + 1023) / 1024;   // 391

  // CSR build (once per launch; reused across all 5 layers)
  hipMemsetAsync(fill, 0, (size_t)N_NODES * 4, stream);
  k_hist<<<(N_EDGES + 255) / 256, 256, 0, stream>>>(dst, fill);
  k_scan1<<<NB1, 256, 0, stream>>>(fill, rp, part);
  k_scan2<<<1, 512, 0, stream>>>(part, NB1);
  k_scan3<<<(N_NODES + 255) / 256, 256, 0, stream>>>(rp, part);
  hipMemsetAsync(fill, 0, (size_t)N_NODES * 4, stream);
  k_scatter<<<(N_EDGES + 255) / 256, 256, 0, stream>>>(src, dst, rp, fill, es);

  k_embed<<<N_NODES * 16 / 256, 256, 0, stream>>>(x, ea, ec, Z0);
  k_wprep<<<NLAYER * 2 * DIM, DIM, 0, stream>>>(W1, W2, wt);

  _Float16* pin = Z0;
  _Float16* pout = Z1;
  for (int l = 0; l < NLAYER; ++l) {
    if (l == 0)
      k_aggx<0><<<N_NODES / 16, 256, 0, stream>>>(pin, rp, es, affine, X);
    else
      k_aggx<1><<<N_NODES / 16, 256, 0, stream>>>(pin, rp, es, affine, X);
    hipMemsetAsync(stats, 0, 64 * 256 * 4, stream);
    k_mlp<<<N_NODES / 64, 256, 0, stream>>>(X, wt + (size_t)l * 2 * DIM * DIM,
                                            b1 + l * DIM, b2 + l * DIM, pout, stats);
    k_fin<<<1, DIM, 0, stream>>>(stats, gamma + l * DIM, beta + l * DIM, affine);
    _Float16* t = pin; pin = pout; pout = t;
  }
  k_out<<<N_NODES * 32 / 256, 256, 0, stream>>>(pin, affine, (float*)d_out);
}